// Round 20
// baseline (303.293 us; speedup 1.0000x reference)
//
#include <hip/hip_runtime.h>
#include <hip/hip_bf16.h>

// Workspace layout (4B units):
// [bcnt:256][pcur:256 (pcur[0]=cursor, pcur[1]=pool-done)][gbuf:G*32][wfbuf:1024]
// [csr_src:SMAX][tile_dst:SMAX/16][Abf:N*16][Bbf:N*16][h1:N*32][h2:N*32]
// A/B packed bf16 (2 ch per uint). csr_tmp ALIASES h1+h2 (h zeroed by pre1
// AFTER place). Record = src(20b)|doff9<<20. Fixed bucket windows (CAP).
// tile_dst cleared to -1 by scatter (strided); place writes live tiles.
// csr_src pads = -1. h1/h2/gbuf hold non-negative float bits (atomicMax uint).

#define NEG_BIG (-3.0e38f)
#define BSHIFT 9                 // bucket: 512 dsts
#define NBMAX 256
#define CHUNKS 8192              // edges per scatter block (8/thread)
#define CAP 32512                // records per bucket window
#define RCAP 16384               // LDS record cache per place block (64 KB)

typedef __attribute__((ext_vector_type(8))) short short8;
typedef __attribute__((ext_vector_type(4))) float f32x4;
typedef __attribute__((ext_vector_type(4))) unsigned uint4v;

__device__ __forceinline__ short bf16r(float f) {
    unsigned u = __float_as_uint(f);
    unsigned r = (u + 0x7FFFu + ((u >> 16) & 1u)) >> 16;
    return (short)r;
}
__device__ __forceinline__ unsigned pack_bf16(float lo, float hi) {
    return ((unsigned)(unsigned short)bf16r(lo)) |
           (((unsigned)(unsigned short)bf16r(hi)) << 16);
}

// pre1: per (node, channel-pair) A/B build + h1/h2 zeroing.
// Last block instead builds the per-lane W fragments for both layers.
__global__ __launch_bounds__(256) void pre1_kernel(
    const float* __restrict__ pos, const float* __restrict__ w1a,
    const float* __restrict__ b1a, const float* __restrict__ w1b,
    const float* __restrict__ w2b, unsigned* __restrict__ Abf,
    unsigned* __restrict__ Bbf, unsigned* __restrict__ wfbuf,
    float* __restrict__ h1, float* __restrict__ h2, int N)
{
    if (blockIdx.x == gridDim.x - 1) {
        int t = threadIdx.x;
        int l = t >> 7, frag = (t >> 6) & 1, lane = t & 63;
        const float* w = l ? w2b : w1b;
        int m16 = lane & 15, kq = (lane >> 4) * 8;
        int cb = frag * 16 + m16;
        unsigned out[4];
#pragma unroll
        for (int p = 0; p < 4; ++p)
            out[p] = pack_bf16(w[(kq + 2 * p) * 32 + cb],
                               w[(kq + 2 * p + 1) * 32 + cb]);
        *(uint4v*)(wfbuf + (size_t)t * 4) = (uint4v){out[0], out[1], out[2], out[3]};
        return;
    }
    int t = blockIdx.x * 256 + threadIdx.x;
    if (t >= N * 16) return;
    int n = t >> 4, c0 = (t & 15) * 2;
    float px = pos[2 * n], py = pos[2 * n + 1];
    float a[2], b[2];
#pragma unroll
    for (int i = 0; i < 2; ++i) {
        int c = c0 + i;
        float w0 = w1a[c], w1 = w1a[32 + c], w2 = w1a[64 + c], w3 = w1a[96 + c];
        a[i] = fmaf(px, w0 + w2, fmaf(py, w1 + w3, b1a[c]));
        b[i] = -(px * w2 + py * w3);
    }
    Abf[t] = pack_bf16(a[0], a[1]);
    Bbf[t] = pack_bf16(b[0], b[1]);
    *(float2*)(h1 + 2 * (size_t)t) = make_float2(0.0f, 0.0f);
    *(float2*)(h2 + 2 * (size_t)t) = make_float2(0.0f, 0.0f);
}

// One thread per node: hrow read once, 32 channels in registers.
__global__ __launch_bounds__(256) void pre2_kernel(
    const float* __restrict__ pos, const float* __restrict__ h1,
    const float* __restrict__ w2a, const float* __restrict__ b2a,
    unsigned* __restrict__ Abf, unsigned* __restrict__ Bbf, int N)
{
    int n = blockIdx.x * 256 + threadIdx.x;
    if (n >= N) return;
    float px = pos[2 * n], py = pos[2 * n + 1];
    const float4* hq = (const float4*)(h1 + (size_t)n * 32);
    float4 hv[8];
#pragma unroll
    for (int q = 0; q < 8; ++q) hv[q] = hq[q];
    float acc[32];
#pragma unroll
    for (int c = 0; c < 32; ++c)
        acc[c] = fmaf(px, w2a[1024 + c], fmaf(py, w2a[1056 + c], b2a[c]));
    const float* hf = (const float*)hv;
#pragma unroll
    for (int k = 0; k < 32; ++k) {
        float hk = hf[k];
#pragma unroll
        for (int c = 0; c < 32; ++c) acc[c] = fmaf(hk, w2a[k * 32 + c], acc[c]);
    }
    unsigned* Arow = Abf + (size_t)n * 16;
    unsigned* Brow = Bbf + (size_t)n * 16;
#pragma unroll
    for (int p = 0; p < 16; ++p) {
        Arow[p] = pack_bf16(acc[2 * p], acc[2 * p + 1]);
        Brow[p] = pack_bf16(-(px * w2a[1024 + 2 * p] + py * w2a[1056 + 2 * p]),
                            -(px * w2a[1025 + 2 * p] + py * w2a[1057 + 2 * p]));
    }
}

// Scatter into fixed per-bucket windows; also clears tile_dst to -1 (strided).
// Edge quads kept in regs (8/thread) across hist -> reserve -> write.
__global__ __launch_bounds__(1024) void bucket_scatter_kernel(
    const int* __restrict__ ei, int* __restrict__ bcnt,
    int* __restrict__ csr_tmp, int* __restrict__ tile_dst,
    int E, int NB, int TMAX)
{
    __shared__ int lh[NBMAX];
    __shared__ int lb[NBMAX];
    int tid = threadIdx.x;
    for (int i = tid; i < NB; i += 1024) lh[i] = 0;
    // clear tile_dst (independent of hist; before barrier)
    for (int i = blockIdx.x * 1024 + tid; i < TMAX; i += gridDim.x * 1024)
        tile_dst[i] = -1;
    __syncthreads();
    const int* dsts = ei + E;
    int base0 = blockIdx.x * CHUNKS;
    int4 sv[2], dv[2];
#pragma unroll
    for (int j = 0; j < 2; ++j) {
        int e = base0 + tid * 4 + j * 4096;
        if (e + 3 < E) {
            sv[j] = *(const int4*)(ei + e);
            dv[j] = *(const int4*)(dsts + e);
        } else {
            int s0 = 0, s1 = 0, s2 = 0, s3 = 0;
            int d0 = -1, d1 = -1, d2 = -1, d3 = -1;
            if (e < E)     { s0 = ei[e];     d0 = dsts[e]; }
            if (e + 1 < E) { s1 = ei[e + 1]; d1 = dsts[e + 1]; }
            if (e + 2 < E) { s2 = ei[e + 2]; d2 = dsts[e + 2]; }
            sv[j] = make_int4(s0, s1, s2, s3);
            dv[j] = make_int4(d0, d1, d2, d3);
        }
        if (dv[j].x >= 0) atomicAdd(&lh[dv[j].x >> BSHIFT], 1);
        if (dv[j].y >= 0) atomicAdd(&lh[dv[j].y >> BSHIFT], 1);
        if (dv[j].z >= 0) atomicAdd(&lh[dv[j].z >> BSHIFT], 1);
        if (dv[j].w >= 0) atomicAdd(&lh[dv[j].w >> BSHIFT], 1);
    }
    __syncthreads();
    for (int i = tid; i < NB; i += 1024) {
        int c = lh[i];
        if (c) {
            int o = atomicAdd(bcnt + i, c);
            if (o > CAP - c) o = CAP - c;   // overflow clamp (never in practice)
            lb[i] = i * CAP + o;
        }
    }
    __syncthreads();
    for (int i = tid; i < NB; i += 1024) lh[i] = 0;
    __syncthreads();
#pragma unroll
    for (int j = 0; j < 2; ++j) {
        int s, d, b, o;
        s = sv[j].x; d = dv[j].x;
        if (d >= 0) { b = d >> BSHIFT; o = atomicAdd(&lh[b], 1);
                      csr_tmp[lb[b] + o] = s | ((d & 511) << 20); }
        s = sv[j].y; d = dv[j].y;
        if (d >= 0) { b = d >> BSHIFT; o = atomicAdd(&lh[b], 1);
                      csr_tmp[lb[b] + o] = s | ((d & 511) << 20); }
        s = sv[j].z; d = dv[j].z;
        if (d >= 0) { b = d >> BSHIFT; o = atomicAdd(&lh[b], 1);
                      csr_tmp[lb[b] + o] = s | ((d & 511) << 20); }
        s = sv[j].w; d = dv[j].w;
        if (d >= 0) { b = d >> BSHIFT; o = atomicAdd(&lh[b], 1);
                      csr_tmp[lb[b] + o] = s | ((d & 511) << 20); }
    }
}

// Place: one 1024-thread block per bucket. Pass A streams the bucket window
// from global ONCE into a 64KB LDS cache while counting per-dst (512). One-
// wave scan -> padded offsets; self-reserve output window via global cursor.
// Pass B re-reads from LDS (global fallback past RCAP), places csr_src,
// fills pads + tile_dst.
__global__ __launch_bounds__(1024) void place_kernel(
    const int* __restrict__ csr_tmp, const int* __restrict__ bcnt,
    int* __restrict__ pcur, int* __restrict__ csr_src,
    int* __restrict__ tile_dst, int N)
{
    __shared__ int rec_cache[RCAP];
    __shared__ int cnt[512], pre[512], cur[512];
    __shared__ int pstart_s;
    int b = blockIdx.x, tid = threadIdx.x;
    int d0 = b << BSHIFT;
    int start = b * CAP;
    int len = bcnt[b];
    if (len > CAP) len = CAP;
    if (tid < 512) cnt[tid] = 0;
    __syncthreads();
    for (int i = tid; i < len; i += 1024) {
        int rec = csr_tmp[start + i];
        if (i < RCAP) rec_cache[i] = rec;
        atomicAdd(&cnt[rec >> 20], 1);
    }
    __syncthreads();
    if (tid < 64) {
        int lane = tid;
        int a[8];
        int s = 0;
#pragma unroll
        for (int j = 0; j < 8; ++j) {
            a[j] = (cnt[8 * lane + j] + 15) & ~15;
            s += a[j];
        }
        int x = s;
#pragma unroll
        for (int d = 1; d < 64; d <<= 1) {
            int t = __shfl_up(x, d, 64);
            if (lane >= d) x += t;
        }
        int total = __shfl(x, 63, 64);
        if (lane == 0) pstart_s = total ? atomicAdd(pcur, total) : 0;
        int run = x - s;
#pragma unroll
        for (int j = 0; j < 8; ++j) {
            pre[8 * lane + j] = run;
            cur[8 * lane + j] = run;
            run += a[j];
        }
    }
    __syncthreads();
    int pstart = pstart_s;
    for (int i = tid; i < len; i += 1024) {
        int rec = (i < RCAP) ? rec_cache[i] : csr_tmp[start + i];
        int p = atomicAdd(&cur[rec >> 20], 1);
        csr_src[pstart + p] = rec & 0xFFFFF;
    }
    if (tid < 512) {
        int d = d0 + tid;
        if (d < N) {
            int c = cnt[tid], pc = (c + 15) & ~15;
            int base = pstart + pre[tid];
            for (int k = c; k < pc; ++k) csr_src[base + k] = -1;
            int tb = base >> 4, nt = pc >> 4;
            for (int k = 0; k < nt; ++k) tile_dst[tb + k] = d;
        }
    }
}

// MFMA edge layer over the PADDED slot list, bf16 A/B. Weight fragments
// pre-built in wfbuf. Register-only reduce with full-tile fast path;
// filtered atomicMax at flush (fp32 bias).
__global__ __launch_bounds__(256, 8) void edge_layer_kernel(
    const int* __restrict__ csr_src, const int* __restrict__ tile_dst,
    const unsigned* __restrict__ Abf, const unsigned* __restrict__ Bbf,
    const unsigned* __restrict__ wf, const float* __restrict__ bias,
    unsigned int* __restrict__ hout)
{
    int tid = threadIdx.x;
    int lane = tid & 63;
    int wv = tid >> 6;
    int wbase = blockIdx.x * 256 + wv * 64;
    int m16 = lane & 15;
    int q = lane >> 4;
    int kq = q * 8;
    int ch = (lane < 16) ? m16 : (16 + m16);

    int td[4];
#pragma unroll
    for (int eg = 0; eg < 4; ++eg) td[eg] = tile_dst[(wbase >> 4) + eg];
    if (td[0] < 0 && td[1] < 0 && td[2] < 0 && td[3] < 0) return;

    short8 bf0 = __builtin_bit_cast(short8, *(const uint4v*)(wf + (size_t)lane * 4));
    short8 bf1 = __builtin_bit_cast(short8, *(const uint4v*)(wf + (size_t)(64 + lane) * 4));
    float myb = bias[ch];
    unsigned int* hch = hout + ch;

    int src[4];
#pragma unroll
    for (int eg = 0; eg < 4; ++eg) {
        int sidx = wbase + eg * 16 + m16;
        src[eg] = (td[eg] >= 0) ? csr_src[sidx] : -1;
    }

    uint4v ua4[4], ub4[4];
#pragma unroll
    for (int eg = 0; eg < 4; ++eg) {
        int brow = (td[eg] >= 0) ? td[eg] : 0;
        int arow = (src[eg] >= 0) ? src[eg] : brow;
        ua4[eg] = *(const uint4v*)(Abf + (size_t)arow * 16 + (kq >> 1));
        ub4[eg] = *(const uint4v*)(Bbf + (size_t)brow * 16 + (kq >> 1));
    }

    f32x4 zero = {0.0f, 0.0f, 0.0f, 0.0f};
    float cv0 = NEG_BIG, cv1 = NEG_BIG;
    int cdst = -1;
#pragma unroll
    for (int eg = 0; eg < 4; ++eg) {
        unsigned long long bal = __ballot(src[eg] >= 0);
        uint4v pk;
#pragma unroll
        for (int d = 0; d < 4; ++d) {
            unsigned uad = ua4[eg][d], ubd = ub4[eg][d];
            float a0 = __uint_as_float(uad << 16);
            float a1 = __uint_as_float(uad & 0xFFFF0000u);
            float b0 = __uint_as_float(ubd << 16);
            float b1 = __uint_as_float(ubd & 0xFFFF0000u);
            float r0 = fmaxf(a0 + b0, 0.0f);
            float r1 = fmaxf(a1 + b1, 0.0f);
            pk[d] = __builtin_amdgcn_perm(__float_as_uint(r1),
                                          __float_as_uint(r0), 0x07060302u);
        }
        short8 af = __builtin_bit_cast(short8, pk);
        f32x4 d0 = __builtin_amdgcn_mfma_f32_16x16x32_bf16(af, bf0, zero, 0, 0, 0);
        f32x4 d1 = __builtin_amdgcn_mfma_f32_16x16x32_bf16(af, bf1, zero, 0, 0, 0);
        float v0, v1;
        if (bal == ~0ull) {
            v0 = fmaxf(fmaxf(d0[0], d0[1]), fmaxf(d0[2], d0[3]));
            v1 = fmaxf(fmaxf(d1[0], d1[1]), fmaxf(d1[2], d1[3]));
        } else {
            v0 = NEG_BIG; v1 = NEG_BIG;
#pragma unroll
            for (int r = 0; r < 4; ++r) {
                bool ok = (bal >> (q * 4 + r)) & 1ull;
                v0 = fmaxf(v0, ok ? d0[r] : NEG_BIG);
                v1 = fmaxf(v1, ok ? d1[r] : NEG_BIG);
            }
        }
        v0 = fmaxf(v0, __shfl_xor(v0, 16, 64));
        v0 = fmaxf(v0, __shfl_xor(v0, 32, 64));
        v1 = fmaxf(v1, __shfl_xor(v1, 16, 64));
        v1 = fmaxf(v1, __shfl_xor(v1, 32, 64));
        int d = td[eg];
        if (d != cdst) {
            if (cdst >= 0 && lane < 32) {
                float x = ((lane < 16) ? cv0 : cv1) + myb;
                if (x > 0.0f)
                    atomicMax(hch + (size_t)cdst * 32, __float_as_uint(x));
            }
            cdst = d; cv0 = v0; cv1 = v1;
        } else {
            cv0 = fmaxf(cv0, v0); cv1 = fmaxf(cv1, v1);
        }
    }
    if (cdst >= 0 && lane < 32) {
        float x = ((lane < 16) ? cv0 : cv1) + myb;
        if (x > 0.0f)
            atomicMax(hch + (size_t)cdst * 32, __float_as_uint(x));
    }
}

// Pool + fused out: last block (completion counter) computes the final GEMM.
__global__ __launch_bounds__(256) void pool_kernel(
    const float* __restrict__ h2, const int* __restrict__ batch,
    unsigned int* __restrict__ gbuf, const float* __restrict__ wc,
    const float* __restrict__ bc, float* __restrict__ out,
    int* __restrict__ done, int N, int G)
{
    int g = blockIdx.x, p = blockIdx.y;
    __shared__ int sbound[2];
    __shared__ float red[256];
    __shared__ int last_s;
    if (threadIdx.x < 2) {
        int target = g + (int)threadIdx.x;
        int lo = 0, hi = N;
        while (lo < hi) {
            int mid = (lo + hi) >> 1;
            if (batch[mid] < target) lo = mid + 1; else hi = mid;
        }
        sbound[threadIdx.x] = lo;
    }
    __syncthreads();
    int start = sbound[0], end = sbound[1];
    int c = threadIdx.x & 31, r = threadIdx.x >> 5;
    float mx = 0.0f;
    for (int n = start + p * 8 + r; n < end; n += 128)
        mx = fmaxf(mx, h2[(size_t)n * 32 + c]);
    red[threadIdx.x] = mx;
    __syncthreads();
    if (r < 4) red[threadIdx.x] = fmaxf(red[threadIdx.x], red[threadIdx.x + 128]);
    __syncthreads();
    if (r < 2) red[threadIdx.x] = fmaxf(red[threadIdx.x], red[threadIdx.x + 64]);
    __syncthreads();
    if (r == 0) {
        float v = fmaxf(red[threadIdx.x], red[threadIdx.x + 32]);
        if (v > 0.0f) atomicMax(gbuf + g * 32 + c, __float_as_uint(v));
    }
    __syncthreads();
    if (threadIdx.x == 0) {
        __threadfence();
        int prev = atomicAdd(done, 1);
        last_s = (prev == G * 16 - 1);
    }
    __syncthreads();
    if (last_s) {
        int t = threadIdx.x;
        if (t < G * 3) {
            int gg = t / 3, j = t % 3;
            float s = bc[j];
#pragma unroll
            for (int cc = 0; cc < 32; ++cc) {
                unsigned u = atomicOr(gbuf + gg * 32 + cc, 0u);  // coherent read
                s = fmaf(__uint_as_float(u), wc[cc * 3 + j], s);
            }
            out[t] = s;
        }
    }
}

extern "C" void kernel_launch(void* const* d_in, const int* in_sizes, int n_in,
                              void* d_out, int out_size, void* d_ws, size_t ws_size,
                              hipStream_t stream) {
    const float* pos = (const float*)d_in[0];
    const float* w1a = (const float*)d_in[1];
    const float* b1a = (const float*)d_in[2];
    const float* w1b = (const float*)d_in[3];
    const float* b1b = (const float*)d_in[4];
    const float* w2a = (const float*)d_in[5];
    const float* b2a = (const float*)d_in[6];
    const float* w2b = (const float*)d_in[7];
    const float* b2b = (const float*)d_in[8];
    const float* wc  = (const float*)d_in[9];
    const float* bc  = (const float*)d_in[10];
    const int* ei    = (const int*)d_in[11];
    const int* batch = (const int*)d_in[12];

    const int N = in_sizes[12];
    const int E = in_sizes[11] / 2;
    const int G = out_size / 3;
    const size_t NC = (size_t)N * 32;
    const int NB = (N + 511) >> BSHIFT;
    const int SMAX = (E + 15 * ((N < E) ? N : E) + 255) & ~255;
    const int TMAX = SMAX >> 4;

    int* bcnt    = (int*)d_ws;          // 256
    int* pcur    = bcnt + 256;          // pcur[0]=cursor, pcur[1]=pool-done
    float* gbuf  = (float*)(pcur + 256);            // G*32 (<=2048)
    unsigned* wfbuf = (unsigned*)(gbuf + 2048);     // 1024
    int* csr_src = (int*)(wfbuf + 1024);            // SMAX
    int* tile_dst = csr_src + SMAX;     // TMAX
    unsigned* Abf = (unsigned*)(tile_dst + TMAX);   // N*16
    unsigned* Bbf = Abf + (size_t)N * 16;           // N*16
    float* h1    = (float*)(Bbf + (size_t)N * 16);
    float* h2    = h1 + NC;
    int* csr_tmp = (int*)h1;            // aliases h1+h2 (N*64 ints >= NB*CAP)

    int npBlocks = ((int)(N * 16) + 255) / 256 + 1;   // +1: wprep block
    int nBlocks  = (N + 255) / 256;
    int sBlocks  = (E + CHUNKS - 1) / CHUNKS;
    int edBlocks = (SMAX + 255) / 256;

    // meta (bcnt + pcur + done) + gbuf zeroed in one shot
    hipMemsetAsync(bcnt, 0, (512 + 2048) * sizeof(int), stream);

    bucket_scatter_kernel<<<sBlocks, 1024, 0, stream>>>(ei, bcnt, csr_tmp,
                                                        tile_dst, E, NB, TMAX);
    place_kernel<<<NB, 1024, 0, stream>>>(csr_tmp, bcnt, pcur,
                                          csr_src, tile_dst, N);
    // pre1 zeroes h1/h2 itself (after place: csr_tmp aliases them) and
    // builds wfbuf in its trailing block.
    pre1_kernel<<<npBlocks, 256, 0, stream>>>(pos, w1a, b1a, w1b, w2b,
                                              Abf, Bbf, wfbuf, h1, h2, N);
    edge_layer_kernel<<<edBlocks, 256, 0, stream>>>(csr_src, tile_dst, Abf, Bbf,
                                                    wfbuf, b1b, (unsigned int*)h1);
    pre2_kernel<<<nBlocks, 256, 0, stream>>>(pos, h1, w2a, b2a, Abf, Bbf, N);
    edge_layer_kernel<<<edBlocks, 256, 0, stream>>>(csr_src, tile_dst, Abf, Bbf,
                                                    wfbuf + 512, b2b,
                                                    (unsigned int*)h2);
    pool_kernel<<<dim3(G, 16), 256, 0, stream>>>(h2, batch,
                                                 (unsigned int*)gbuf,
                                                 wc, bc, (float*)d_out,
                                                 pcur + 1, N, G);
}